// Round 4
// baseline (10397.668 us; speedup 1.0000x reference)
//
#include <hip/hip_runtime.h>
#include <stdint.h>

typedef __bf16 bf16_t;
typedef _Float16 fp16_t;
typedef bf16_t bf16x8 __attribute__((ext_vector_type(8)));
typedef fp16_t fp16x4 __attribute__((ext_vector_type(4)));
typedef float f32x4 __attribute__((ext_vector_type(4)));

#define LOG2E 1.44269504088896340736f

__device__ __forceinline__ float sigm(float x) {
    return __builtin_amdgcn_rcpf(1.f + __builtin_amdgcn_exp2f(-LOG2E * x));
}
__device__ __forceinline__ float tanh_(float x) {
    return 1.f - 2.f * __builtin_amdgcn_rcpf(1.f + __builtin_amdgcn_exp2f((2.f * LOG2E) * x));
}

// ---------------------------------------------------------------------------
// Kernel 1: fold fuse_W2@fuse_W1 into a single 340-vector + scalar
// ---------------------------------------------------------------------------
__global__ void prep_fuse(const float* __restrict__ W1, const float* __restrict__ b1,
                          const float* __restrict__ W2, const float* __restrict__ b2,
                          float* __restrict__ v) {
    int u = threadIdx.x;
    if (u < 340) {
        float s = 0.f;
        for (int j = 0; j < 64; j++) s += W2[j] * W1[j * 340 + u];
        v[u] = s;
    } else if (u == 340) {
        float s = 0.f;
        for (int j = 0; j < 64; j++) s += W2[j] * b1[j];
        v[340] = s + b2[0];
    }
}

// ---------------------------------------------------------------------------
// Kernel 2: input GEMMs. M-block = 16b x 16t (256 rows), BN=128, BK=32.
// Split-bf16 A. Register-prefetch pipeline. Output [t][bg][u][b16][g] fp16,
// bias = b_ih + b_hh folded in.
// ---------------------------------------------------------------------------
struct ModGemm {
    const float* x; const float* w; const float* bih; const float* bhh; fp16_t* xg;
    int D; int KB; int N4; int HP; int hshift;   // hshift 0 => HR=20 (E)
};
struct GemmArgs { ModGemm m[4]; int slot_mi[11]; int slot_nb[11]; };

__global__ __launch_bounds__(512) void gemm_all(GemmArgs ga) {
    __shared__ bf16_t sAh[256 * 40];
    __shared__ bf16_t sAl[256 * 40];
    __shared__ bf16_t sB[128 * 40];
    const int slot = blockIdx.y;
    const ModGemm mg = ga.m[ga.slot_mi[slot]];
    const int ncol0 = ga.slot_nb[slot] << 7;
    const int tid = threadIdx.x;
    const int w = tid >> 6, l = tid & 63, lm = l & 15, q = l >> 4;
    const int wm = w & 3, wn = w >> 2;
    const int bg = blockIdx.x & 3, t0 = (blockIdx.x >> 2) << 4;
    const int D = mg.D, N4 = mg.N4, KB = mg.KB;
    const int ra = tid >> 1, ca = (tid & 1) << 4;   // A: 2 thr/row, 16 floats
    const int rb = tid >> 2, cb = (tid & 3) << 3;   // B: 4 thr/row, 8 floats
    const int bA = (bg << 4) + (ra >> 4), tA = t0 + (ra & 15);
    const float* xrow = mg.x + (size_t)((bA << 9) + tA) * D;
    const int wr = ncol0 + rb;
    const bool vB = wr < N4;
    const float* wrow = mg.w + (size_t)(vB ? wr : 0) * D;

    float aR[16], bR[8];
    auto LOAD = [&](int kb) {
        const int k0 = kb << 5;
        if (k0 + ca + 16 <= D) {
            const float* s = xrow + k0 + ca;
#pragma unroll
            for (int j = 0; j < 8; j++) { float2 f = *(const float2*)(s + 2 * j); aR[2 * j] = f.x; aR[2 * j + 1] = f.y; }
        } else {
#pragma unroll
            for (int j = 0; j < 16; j++) { int k = k0 + ca + j; aR[j] = (k < D) ? xrow[k] : 0.f; }
        }
        if (vB && k0 + cb + 8 <= D) {
            const float* s = wrow + k0 + cb;
#pragma unroll
            for (int j = 0; j < 4; j++) { float2 f = *(const float2*)(s + 2 * j); bR[2 * j] = f.x; bR[2 * j + 1] = f.y; }
        } else {
#pragma unroll
            for (int j = 0; j < 8; j++) { int k = k0 + cb + j; bR[j] = (vB && k < D) ? wrow[k] : 0.f; }
        }
    };
    auto STORE = [&]() {
        union { bf16_t e[16]; bf16x8 v[2]; } uh, ul;
#pragma unroll
        for (int j = 0; j < 16; j++) {
            bf16_t h = (bf16_t)aR[j];
            uh.e[j] = h; ul.e[j] = (bf16_t)(aR[j] - (float)h);
        }
        *(bf16x8*)&sAh[ra * 40 + ca] = uh.v[0];
        *(bf16x8*)&sAh[ra * 40 + ca + 8] = uh.v[1];
        *(bf16x8*)&sAl[ra * 40 + ca] = ul.v[0];
        *(bf16x8*)&sAl[ra * 40 + ca + 8] = ul.v[1];
        union { bf16_t e[8]; bf16x8 v; } ub;
#pragma unroll
        for (int j = 0; j < 8; j++) ub.e[j] = (bf16_t)bR[j];
        *(bf16x8*)&sB[rb * 40 + cb] = ub.v;
    };

    f32x4 acc[4][4];
#pragma unroll
    for (int a = 0; a < 4; a++)
#pragma unroll
        for (int b = 0; b < 4; b++) acc[a][b] = 0.f;

    LOAD(0); STORE(); __syncthreads();
    for (int kb = 0; kb < KB; kb++) {
        if (kb + 1 < KB) LOAD(kb + 1);
        bf16x8 ah[4], al[4];
#pragma unroll
        for (int mt = 0; mt < 4; mt++) {
            int row = (wm << 6) + (mt << 4) + lm;
            ah[mt] = *(const bf16x8*)&sAh[row * 40 + (q << 3)];
            al[mt] = *(const bf16x8*)&sAl[row * 40 + (q << 3)];
        }
#pragma unroll
        for (int nt = 0; nt < 4; nt++) {
            bf16x8 bfv = *(const bf16x8*)&sB[((wn << 6) + (nt << 4) + lm) * 40 + (q << 3)];
#pragma unroll
            for (int mt = 0; mt < 4; mt++) {
                acc[mt][nt] = __builtin_amdgcn_mfma_f32_16x16x32_bf16(ah[mt], bfv, acc[mt][nt], 0, 0, 0);
                acc[mt][nt] = __builtin_amdgcn_mfma_f32_16x16x32_bf16(al[mt], bfv, acc[mt][nt], 0, 0, 0);
            }
        }
        __syncthreads();
        if (kb + 1 < KB) { STORE(); __syncthreads(); }
    }
    // ---- epilogue: +(b_ih+b_hh), store fp16 to [t][bg][u][b16][g]
#pragma unroll
    for (int nt = 0; nt < 4; nt++) {
        int col = ncol0 + (wn << 6) + (nt << 4) + lm;
        if (col >= N4) continue;
        float bias = mg.bih[col] + mg.bhh[col];
        int g, u;
        if (mg.hshift) { g = col >> mg.hshift; u = col & ((1 << mg.hshift) - 1); }
        else { g = col / 20; u = col - g * 20; }
#pragma unroll
        for (int mt = 0; mt < 4; mt++) {
            int bl = (wm << 2) + mt;
#pragma unroll
            for (int r = 0; r < 4; r++) {
                int t = t0 + (q << 2) + r;
                size_t dst = ((((size_t)t * 4 + bg) * mg.HP + u) * 16 + bl) * 4 + g;
                mg.xg[dst] = (fp16_t)(acc[mt][nt][r] + bias);
            }
        }
    }
}

// ---------------------------------------------------------------------------
// Kernel 3: recurrent scan, swapped MFMA roles: D[u][b] = W[u][:] x h[:][b].
// A-operand = W (registers), B-operand = h (LDS). 16 blocks = 4 mods x 4
// batch-groups of 16. One barrier per step.
// ---------------------------------------------------------------------------
struct ModRec {
    const float* whh; const int* present; const fp16_t* xg;
    int voff; int woff;
};
struct RecArgs {
    ModRec m[4];
    const float* vvec;
    float* spart;   // [22 wave-slots][4 grp][512 t][16 b]
};

template <int HP, int HR>
__device__ void rec_mfma(const ModRec M, int grp, float* __restrict__ spart,
                         const float* __restrict__ vvec,
                         uint32_t* presw, bf16_t* hb0, bf16_t* hb1, int tid) {
    constexpr int KT = HP / 32, TPG = HP / 16, HPs = HP + 8;
    const int w = tid >> 6, l = tid & 63, lm = l & 15, q = l >> 4;
    const int b0 = grp << 4;
    const bool act = (w < TPG);

    for (int i = tid; i < 16 * HPs; i += 512) { hb0[i] = (bf16_t)0.f; hb1[i] = (bf16_t)0.f; }
    if (tid < 256) {
        int b = tid >> 4, wd = tid & 15;
        const int* pp = M.present + ((b0 + b) << 9) + (wd << 5);
        uint32_t word = 0;
#pragma unroll 8
        for (int j = 0; j < 32; j++) word |= (pp[j] != 0 ? 1u : 0u) << j;
        presw[(b << 4) + wd] = word;
    }

    bf16x8 wf[4][KT];
    float vvr[4];
    const int u0 = w << 4;
    if (act) {
#pragma unroll
        for (int g = 0; g < 4; g++) {
            int urow = u0 + lm;
#pragma unroll
            for (int kt = 0; kt < KT; kt++) {
                union { bf16_t e[8]; bf16x8 v; } uu;
#pragma unroll
                for (int j = 0; j < 8; j++) {
                    int k = (kt << 5) + (q << 3) + j;
                    float f = (urow < HR && k < HR) ? M.whh[(size_t)(g * HR + urow) * HR + k] : 0.f;
                    uu.e[j] = (bf16_t)f;
                }
                wf[g][kt] = uu.v;
            }
        }
#pragma unroll
        for (int r = 0; r < 4; r++) {
            int u = u0 + (q << 2) + r;
            vvr[r] = (u < HR) ? vvec[M.voff + u] : 0.f;
        }
    }
    const size_t tstride = (size_t)256 * HP;
    const fp16_t* px[4];
#pragma unroll
    for (int r = 0; r < 4; r++) {
        int u = u0 + (q << 2) + r;
        px[r] = M.xg + (((size_t)grp * HP + u) << 6) + (lm << 2);
    }
    fp16x4 xv[4][4];
    if (act) {
#pragma unroll
        for (int s = 0; s < 4; s++)
#pragma unroll
            for (int r = 0; r < 4; r++)
                xv[s][r] = *(const fp16x4*)(px[r] + (size_t)s * tstride);
    }
    float h_st[4] = {0, 0, 0, 0}, c_st[4] = {0, 0, 0, 0};
    float* spw = spart + (size_t)(((M.woff + w) << 2) + grp) * 8192;
    uint32_t pw = 0;
    __syncthreads();

    auto step = [&](int t, const bf16_t* hbR, bf16_t* hbW) {
        if (act) {
            if ((t & 31) == 0) pw = presw[(lm << 4) + (t >> 5)];
            bf16x8 af[KT];
#pragma unroll
            for (int kt = 0; kt < KT; kt++)
                af[kt] = *(const bf16x8*)&hbR[lm * HPs + (kt << 5) + (q << 3)];
            const int s = t & 3;
            f32x4 accv[4];
#pragma unroll
            for (int g = 0; g < 4; g++)
#pragma unroll
                for (int r = 0; r < 4; r++)
                    accv[g][r] = (float)xv[s][r][g];
            if (t + 4 < 512) {
#pragma unroll
                for (int r = 0; r < 4; r++)
                    xv[s][r] = *(const fp16x4*)(px[r] + (size_t)(t + 4) * tstride);
            }
            // A-operand = W (m=u), B-operand = h (n=b)  ->  D[u][b]
#pragma unroll
            for (int kt = 0; kt < KT; kt++)
#pragma unroll
                for (int g = 0; g < 4; g++)
                    accv[g] = __builtin_amdgcn_mfma_f32_16x16x32_bf16(wf[g][kt], af[kt], accv[g], 0, 0, 0);
            const bool pb = (pw >> (t & 31)) & 1;
            float cr = 0.f;
#pragma unroll
            for (int r = 0; r < 4; r++) {
                float gi = sigm(accv[0][r]);
                float gf = sigm(accv[1][r]);
                float gg = tanh_(accv[2][r]);
                float go = sigm(accv[3][r]);
                float cn = gf * c_st[r] + gi * gg;
                float hn = go * tanh_(cn);
                float h2 = pb ? hn : h_st[r];
                float c2 = pb ? cn : c_st[r];
                if (HR < HP) {
                    int u = u0 + (q << 2) + r;
                    if (u >= HR) h2 = 0.f;
                }
                h_st[r] = h2; c_st[r] = c2;
                cr += h2 * vvr[r];
            }
            union { bf16_t e[4]; unsigned long long d; } hp_;
#pragma unroll
            for (int r = 0; r < 4; r++) hp_.e[r] = (bf16_t)h_st[r];
            *(unsigned long long*)&hbW[lm * HPs + u0 + (q << 2)] = hp_.d;
            cr += __shfl_xor(cr, 16);
            cr += __shfl_xor(cr, 32);
            if (q == 0) spw[(t << 4) + lm] = cr;
        }
        __syncthreads();
    };

    for (int t = 0; t < 512; t += 2) {
        step(t, hb0, hb1);
        step(t + 1, hb1, hb0);
    }
}

__global__ __launch_bounds__(512) void rec_all(RecArgs ra) {
    __shared__ uint32_t presw[256];
    __shared__ bf16_t hb0[16 * 136];
    __shared__ bf16_t hb1[16 * 136];
    const int tid = threadIdx.x;
    const int bid = blockIdx.x;
    const int mi = bid >> 2, grp = bid & 3;   // 0=L,1=E,2=A,3=I
    const ModRec M = ra.m[mi];
    if (mi == 0)      rec_mfma<128, 128>(M, grp, ra.spart, ra.vvec, presw, hb0, hb1, tid);
    else if (mi == 1) rec_mfma<32, 20>(M, grp, ra.spart, ra.vvec, presw, hb0, hb1, tid);
    else if (mi == 2) rec_mfma<64, 64>(M, grp, ra.spart, ra.vvec, presw, hb0, hb1, tid);
    else              rec_mfma<128, 128>(M, grp, ra.spart, ra.vvec, presw, hb0, hb1, tid);
}

// ---------------------------------------------------------------------------
// Kernel 4: out[b][t] = mask * (sum over 22 wave-slots + c0)
// wave-slot bases: L:0(8), E:8(2), A:10(4), I:14(8)
// ---------------------------------------------------------------------------
__global__ void fuse_out(const float* __restrict__ sp, const float* __restrict__ v,
                         const float* __restrict__ masks, float* __restrict__ out) {
    int i = threadIdx.x + blockIdx.x * 256;
    int b = i >> 9, t = i & 511;
    int bg = b >> 4, bl = b & 15;
    float c0 = v[340];
    float s = 0.f;
#pragma unroll
    for (int sl = 0; sl < 22; sl++)
        s += sp[(size_t)((sl << 2) + bg) * 8192 + (t << 4) + bl];
    out[i] = masks[i] * (s + c0);
}

// ---------------------------------------------------------------------------
extern "C" void kernel_launch(void* const* d_in, const int* in_sizes, int n_in,
                              void* d_out, int out_size, void* d_ws, size_t ws_size,
                              hipStream_t stream) {
    const float* xL = (const float*)d_in[0];
    const int*   pL = (const int*)d_in[1];
    const float* WihL = (const float*)d_in[2];
    const float* WhhL = (const float*)d_in[3];
    const float* bihL = (const float*)d_in[4];
    const float* bhhL = (const float*)d_in[5];
    const float* xE = (const float*)d_in[6];
    const int*   pE = (const int*)d_in[7];
    const float* WihE = (const float*)d_in[8];
    const float* WhhE = (const float*)d_in[9];
    const float* bihE = (const float*)d_in[10];
    const float* bhhE = (const float*)d_in[11];
    const float* xA = (const float*)d_in[12];
    const int*   pA = (const int*)d_in[13];
    const float* WihA = (const float*)d_in[14];
    const float* WhhA = (const float*)d_in[15];
    const float* bihA = (const float*)d_in[16];
    const float* bhhA = (const float*)d_in[17];
    const float* xI = (const float*)d_in[18];
    const int*   pI = (const int*)d_in[19];
    const float* WihI = (const float*)d_in[20];
    const float* WhhI = (const float*)d_in[21];
    const float* bihI = (const float*)d_in[22];
    const float* bhhI = (const float*)d_in[23];
    const float* masks = (const float*)d_in[25];
    const float* fW1 = (const float*)d_in[26];
    const float* fb1 = (const float*)d_in[27];
    const float* fW2 = (const float*)d_in[28];
    const float* fb2 = (const float*)d_in[29];

    char* ws = (char*)d_ws;
    float* v     = (float*)ws;                           // 344 floats
    float* spart = (float*)(ws + (1 << 16));             // 88 * 8192 floats = 2.75 MB
    char* xgbase = ws + (1 << 16) + (3 << 20);
    fp16_t* xgL = (fp16_t*)xgbase;                            // 512*4*128*64 fp16 = 32 MB
    fp16_t* xgI = xgL + (size_t)512 * 4 * 128 * 64;           // 32 MB
    fp16_t* xgA = xgI + (size_t)512 * 4 * 128 * 64;           // 16 MB
    fp16_t* xgE = xgA + (size_t)512 * 4 * 64 * 64;            // 8 MB

    prep_fuse<<<dim3(1), dim3(512), 0, stream>>>(fW1, fb1, fW2, fb2, v);

    GemmArgs ga;
    ga.m[0] = {xL, WihL, bihL, bhhL, xgL, 300,  10, 512, 128, 7};
    ga.m[1] = {xE, WihE, bihE, bhhE, xgE, 30,   1,  80,  32,  0};
    ga.m[2] = {xA, WihA, bihA, bhhA, xgA, 88,   3,  256, 64,  6};
    ga.m[3] = {xI, WihI, bihI, bhhI, xgI, 1000, 32, 512, 128, 7};
    const int mi_tab[11] = {0, 0, 0, 0, 3, 3, 3, 3, 2, 2, 1};
    const int nb_tab[11] = {0, 1, 2, 3, 0, 1, 2, 3, 0, 1, 0};
    for (int i = 0; i < 11; i++) { ga.slot_mi[i] = mi_tab[i]; ga.slot_nb[i] = nb_tab[i]; }
    gemm_all<<<dim3(128, 11), dim3(512), 0, stream>>>(ga);

    RecArgs ra;
    ra.m[0] = {WhhL, pL, xgL, 0,   0};
    ra.m[1] = {WhhE, pE, xgE, 128, 8};
    ra.m[2] = {WhhA, pA, xgA, 148, 10};
    ra.m[3] = {WhhI, pI, xgI, 212, 14};
    ra.vvec = v;
    ra.spart = spart;
    rec_all<<<dim3(16), dim3(512), 0, stream>>>(ra);

    fuse_out<<<dim3(128), dim3(256), 0, stream>>>(spart, v, masks, (float*)d_out);
}

// Round 5
// 1183.095 us; speedup vs baseline: 8.7885x; 8.7885x over previous
//
#include <hip/hip_runtime.h>
#include <stdint.h>

typedef __bf16 bf16_t;
typedef _Float16 fp16_t;
typedef bf16_t bf16x8 __attribute__((ext_vector_type(8)));
typedef fp16_t fp16x4 __attribute__((ext_vector_type(4)));
typedef float f32x4 __attribute__((ext_vector_type(4)));

#define LOG2E 1.44269504088896340736f

__device__ __forceinline__ float sigm(float x) {
    return __builtin_amdgcn_rcpf(1.f + __builtin_amdgcn_exp2f(-LOG2E * x));
}
__device__ __forceinline__ float tanh_(float x) {
    return 1.f - 2.f * __builtin_amdgcn_rcpf(1.f + __builtin_amdgcn_exp2f((2.f * LOG2E) * x));
}

// ---------------------------------------------------------------------------
// Kernel 1: fold fuse_W2@fuse_W1 into a single 340-vector + scalar
// ---------------------------------------------------------------------------
__global__ void prep_fuse(const float* __restrict__ W1, const float* __restrict__ b1,
                          const float* __restrict__ W2, const float* __restrict__ b2,
                          float* __restrict__ v) {
    int u = threadIdx.x;
    if (u < 340) {
        float s = 0.f;
        for (int j = 0; j < 64; j++) s += W2[j] * W1[j * 340 + u];
        v[u] = s;
    } else if (u == 340) {
        float s = 0.f;
        for (int j = 0; j < 64; j++) s += W2[j] * b1[j];
        v[340] = s + b2[0];
    }
}

// ---------------------------------------------------------------------------
// Kernel 2: input GEMMs. M-block = 16b x 16t (256 rows), BN=128, BK=32.
// Split-bf16 A. Register-prefetch pipeline. Output [t][bg][u][b16][g] fp16,
// bias = b_ih + b_hh folded in.
// ---------------------------------------------------------------------------
struct ModGemm {
    const float* x; const float* w; const float* bih; const float* bhh; fp16_t* xg;
    int D; int KB; int N4; int HP; int hshift;   // hshift 0 => HR=20 (E)
};
struct GemmArgs { ModGemm m[4]; int slot_mi[11]; int slot_nb[11]; };

__global__ __launch_bounds__(512) void gemm_all(GemmArgs ga) {
    __shared__ bf16_t sAh[256 * 40];
    __shared__ bf16_t sAl[256 * 40];
    __shared__ bf16_t sB[128 * 40];
    const int slot = blockIdx.y;
    const ModGemm mg = ga.m[ga.slot_mi[slot]];
    const int ncol0 = ga.slot_nb[slot] << 7;
    const int tid = threadIdx.x;
    const int w = tid >> 6, l = tid & 63, lm = l & 15, q = l >> 4;
    const int wm = w & 3, wn = w >> 2;
    const int bg = blockIdx.x & 3, t0 = (blockIdx.x >> 2) << 4;
    const int D = mg.D, N4 = mg.N4, KB = mg.KB;
    const int ra = tid >> 1, ca = (tid & 1) << 4;   // A: 2 thr/row, 16 floats
    const int rb = tid >> 2, cb = (tid & 3) << 3;   // B: 4 thr/row, 8 floats
    const int bA = (bg << 4) + (ra >> 4), tA = t0 + (ra & 15);
    const float* xrow = mg.x + (size_t)((bA << 9) + tA) * D;
    const int wr = ncol0 + rb;
    const bool vB = wr < N4;
    const float* wrow = mg.w + (size_t)(vB ? wr : 0) * D;

    float aR[16], bR[8];
    auto LOAD = [&](int kb) {
        const int k0 = kb << 5;
        if (k0 + ca + 16 <= D) {
            const float* s = xrow + k0 + ca;
#pragma unroll
            for (int j = 0; j < 8; j++) { float2 f = *(const float2*)(s + 2 * j); aR[2 * j] = f.x; aR[2 * j + 1] = f.y; }
        } else {
#pragma unroll
            for (int j = 0; j < 16; j++) { int k = k0 + ca + j; aR[j] = (k < D) ? xrow[k] : 0.f; }
        }
        if (vB && k0 + cb + 8 <= D) {
            const float* s = wrow + k0 + cb;
#pragma unroll
            for (int j = 0; j < 4; j++) { float2 f = *(const float2*)(s + 2 * j); bR[2 * j] = f.x; bR[2 * j + 1] = f.y; }
        } else {
#pragma unroll
            for (int j = 0; j < 8; j++) { int k = k0 + cb + j; bR[j] = (vB && k < D) ? wrow[k] : 0.f; }
        }
    };
    auto STORE = [&]() {
        union { bf16_t e[16]; bf16x8 v[2]; } uh, ul;
#pragma unroll
        for (int j = 0; j < 16; j++) {
            bf16_t h = (bf16_t)aR[j];
            uh.e[j] = h; ul.e[j] = (bf16_t)(aR[j] - (float)h);
        }
        *(bf16x8*)&sAh[ra * 40 + ca] = uh.v[0];
        *(bf16x8*)&sAh[ra * 40 + ca + 8] = uh.v[1];
        *(bf16x8*)&sAl[ra * 40 + ca] = ul.v[0];
        *(bf16x8*)&sAl[ra * 40 + ca + 8] = ul.v[1];
        union { bf16_t e[8]; bf16x8 v; } ub;
#pragma unroll
        for (int j = 0; j < 8; j++) ub.e[j] = (bf16_t)bR[j];
        *(bf16x8*)&sB[rb * 40 + cb] = ub.v;
    };

    f32x4 acc[4][4];
#pragma unroll
    for (int a = 0; a < 4; a++)
#pragma unroll
        for (int b = 0; b < 4; b++) acc[a][b] = 0.f;

    LOAD(0); STORE(); __syncthreads();
    for (int kb = 0; kb < KB; kb++) {
        if (kb + 1 < KB) LOAD(kb + 1);
        bf16x8 ah[4], al[4];
#pragma unroll
        for (int mt = 0; mt < 4; mt++) {
            int row = (wm << 6) + (mt << 4) + lm;
            ah[mt] = *(const bf16x8*)&sAh[row * 40 + (q << 3)];
            al[mt] = *(const bf16x8*)&sAl[row * 40 + (q << 3)];
        }
#pragma unroll
        for (int nt = 0; nt < 4; nt++) {
            bf16x8 bfv = *(const bf16x8*)&sB[((wn << 6) + (nt << 4) + lm) * 40 + (q << 3)];
#pragma unroll
            for (int mt = 0; mt < 4; mt++) {
                acc[mt][nt] = __builtin_amdgcn_mfma_f32_16x16x32_bf16(ah[mt], bfv, acc[mt][nt], 0, 0, 0);
                acc[mt][nt] = __builtin_amdgcn_mfma_f32_16x16x32_bf16(al[mt], bfv, acc[mt][nt], 0, 0, 0);
            }
        }
        __syncthreads();
        if (kb + 1 < KB) { STORE(); __syncthreads(); }
    }
    // ---- epilogue: +(b_ih+b_hh), store fp16 to [t][bg][u][b16][g]
#pragma unroll
    for (int nt = 0; nt < 4; nt++) {
        int col = ncol0 + (wn << 6) + (nt << 4) + lm;
        if (col >= N4) continue;
        float bias = mg.bih[col] + mg.bhh[col];
        int g, u;
        if (mg.hshift) { g = col >> mg.hshift; u = col & ((1 << mg.hshift) - 1); }
        else { g = col / 20; u = col - g * 20; }
#pragma unroll
        for (int mt = 0; mt < 4; mt++) {
            int bl = (wm << 2) + mt;
#pragma unroll
            for (int r = 0; r < 4; r++) {
                int t = t0 + (q << 2) + r;
                size_t dst = ((((size_t)t * 4 + bg) * mg.HP + u) * 16 + bl) * 4 + g;
                mg.xg[dst] = (fp16_t)(acc[mt][nt][r] + bias);
            }
        }
    }
}

// ---------------------------------------------------------------------------
// Kernel 3: recurrent scan. D[u][b] = W[u][:] x h[:][b]; A=W (regs), B=h (LDS).
// 16 blocks = 4 mods x 4 batch-groups of 16. One barrier per step.
// t-loop unrolled x4 so the xv slot index is COMPILE-TIME (keeps xv in VGPRs —
// dynamic indexing demotes it to scratch, the R4 10x regression).
// ---------------------------------------------------------------------------
struct ModRec {
    const float* whh; const int* present; const fp16_t* xg;
    int voff; int woff;
};
struct RecArgs {
    ModRec m[4];
    const float* vvec;
    float* spart;   // [22 wave-slots][4 grp][512 t][16 b]
};

template <int HP, int HR>
__device__ __forceinline__ void rec_step(
    int t, bool act, int u0, int lm, int q,
    const bf16x8 (&wf)[4][HP / 32], const float (&vvr)[4],
    fp16x4 (&xvs)[4], const fp16_t* const (&px)[4], size_t tstride,
    float (&h_st)[4], float (&c_st)[4], uint32_t& pw,
    const uint32_t* __restrict__ presw,
    const bf16_t* __restrict__ hbR, bf16_t* __restrict__ hbW,
    float* __restrict__ spw) {
    constexpr int KT = HP / 32, HPs = HP + 8;
    if (act) {
        if ((t & 31) == 0) pw = presw[(lm << 4) + (t >> 5)];
        bf16x8 af[KT];
#pragma unroll
        for (int kt = 0; kt < KT; kt++)
            af[kt] = *(const bf16x8*)&hbR[lm * HPs + (kt << 5) + (q << 3)];
        f32x4 accv[4];
#pragma unroll
        for (int g = 0; g < 4; g++)
#pragma unroll
            for (int r = 0; r < 4; r++)
                accv[g][r] = (float)xvs[r][g];
        if (t + 4 < 512) {
#pragma unroll
            for (int r = 0; r < 4; r++)
                xvs[r] = *(const fp16x4*)(px[r] + (size_t)(t + 4) * tstride);
        }
        // A-operand = W (m=u), B-operand = h (n=b)  ->  D[u][b]
#pragma unroll
        for (int kt = 0; kt < KT; kt++)
#pragma unroll
            for (int g = 0; g < 4; g++)
                accv[g] = __builtin_amdgcn_mfma_f32_16x16x32_bf16(wf[g][kt], af[kt], accv[g], 0, 0, 0);
        const bool pb = (pw >> (t & 31)) & 1;
        float cr = 0.f;
#pragma unroll
        for (int r = 0; r < 4; r++) {
            float gi = sigm(accv[0][r]);
            float gf = sigm(accv[1][r]);
            float gg = tanh_(accv[2][r]);
            float go = sigm(accv[3][r]);
            float cn = gf * c_st[r] + gi * gg;
            float hn = go * tanh_(cn);
            float h2 = pb ? hn : h_st[r];
            float c2 = pb ? cn : c_st[r];
            if (HR < HP) {
                int u = u0 + (q << 2) + r;
                if (u >= HR) h2 = 0.f;
            }
            h_st[r] = h2; c_st[r] = c2;
            cr += h2 * vvr[r];
        }
        union { bf16_t e[4]; unsigned long long d; } hp_;
#pragma unroll
        for (int r = 0; r < 4; r++) hp_.e[r] = (bf16_t)h_st[r];
        *(unsigned long long*)&hbW[lm * HPs + u0 + (q << 2)] = hp_.d;
        cr += __shfl_xor(cr, 16);
        cr += __shfl_xor(cr, 32);
        if (q == 0) spw[(t << 4) + lm] = cr;
    }
    __syncthreads();
}

template <int HP, int HR>
__device__ void rec_mfma(const ModRec M, int grp, float* __restrict__ spart,
                         const float* __restrict__ vvec,
                         uint32_t* presw, bf16_t* hb0, bf16_t* hb1, int tid) {
    constexpr int KT = HP / 32, TPG = HP / 16, HPs = HP + 8;
    const int w = tid >> 6, l = tid & 63, lm = l & 15, q = l >> 4;
    const int b0 = grp << 4;
    const bool act = (w < TPG);

    for (int i = tid; i < 16 * HPs; i += 512) { hb0[i] = (bf16_t)0.f; hb1[i] = (bf16_t)0.f; }
    if (tid < 256) {
        int b = tid >> 4, wd = tid & 15;
        const int* pp = M.present + ((b0 + b) << 9) + (wd << 5);
        uint32_t word = 0;
#pragma unroll 8
        for (int j = 0; j < 32; j++) word |= (pp[j] != 0 ? 1u : 0u) << j;
        presw[(b << 4) + wd] = word;
    }

    bf16x8 wf[4][KT];
    float vvr[4];
    const int u0 = w << 4;
    if (act) {
#pragma unroll
        for (int g = 0; g < 4; g++) {
            int urow = u0 + lm;
#pragma unroll
            for (int kt = 0; kt < KT; kt++) {
                union { bf16_t e[8]; bf16x8 v; } uu;
#pragma unroll
                for (int j = 0; j < 8; j++) {
                    int k = (kt << 5) + (q << 3) + j;
                    float f = (urow < HR && k < HR) ? M.whh[(size_t)(g * HR + urow) * HR + k] : 0.f;
                    uu.e[j] = (bf16_t)f;
                }
                wf[g][kt] = uu.v;
            }
        }
#pragma unroll
        for (int r = 0; r < 4; r++) {
            int u = u0 + (q << 2) + r;
            vvr[r] = (u < HR) ? vvec[M.voff + u] : 0.f;
        }
    }
    const size_t tstride = (size_t)256 * HP;
    const fp16_t* px[4];
#pragma unroll
    for (int r = 0; r < 4; r++) {
        int u = u0 + (q << 2) + r;
        px[r] = M.xg + (((size_t)grp * HP + u) << 6) + (lm << 2);
    }
    fp16x4 xv[4][4];
    if (act) {
#pragma unroll
        for (int s = 0; s < 4; s++)
#pragma unroll
            for (int r = 0; r < 4; r++)
                xv[s][r] = *(const fp16x4*)(px[r] + (size_t)s * tstride);
    }
    float h_st[4] = {0, 0, 0, 0}, c_st[4] = {0, 0, 0, 0};
    float* spw = spart + (size_t)(((M.woff + w) << 2) + grp) * 8192;
    uint32_t pw = 0;
    __syncthreads();

    for (int t0 = 0; t0 < 512; t0 += 4) {
        rec_step<HP, HR>(t0 + 0, act, u0, lm, q, wf, vvr, xv[0], px, tstride, h_st, c_st, pw, presw, hb0, hb1, spw);
        rec_step<HP, HR>(t0 + 1, act, u0, lm, q, wf, vvr, xv[1], px, tstride, h_st, c_st, pw, presw, hb1, hb0, spw);
        rec_step<HP, HR>(t0 + 2, act, u0, lm, q, wf, vvr, xv[2], px, tstride, h_st, c_st, pw, presw, hb0, hb1, spw);
        rec_step<HP, HR>(t0 + 3, act, u0, lm, q, wf, vvr, xv[3], px, tstride, h_st, c_st, pw, presw, hb1, hb0, spw);
    }
}

__global__ __launch_bounds__(512) void rec_all(RecArgs ra) {
    __shared__ uint32_t presw[256];
    __shared__ bf16_t hb0[16 * 136];
    __shared__ bf16_t hb1[16 * 136];
    const int tid = threadIdx.x;
    const int bid = blockIdx.x;
    const int mi = bid >> 2, grp = bid & 3;   // 0=L,1=E,2=A,3=I
    const ModRec M = ra.m[mi];
    if (mi == 0)      rec_mfma<128, 128>(M, grp, ra.spart, ra.vvec, presw, hb0, hb1, tid);
    else if (mi == 1) rec_mfma<32, 20>(M, grp, ra.spart, ra.vvec, presw, hb0, hb1, tid);
    else if (mi == 2) rec_mfma<64, 64>(M, grp, ra.spart, ra.vvec, presw, hb0, hb1, tid);
    else              rec_mfma<128, 128>(M, grp, ra.spart, ra.vvec, presw, hb0, hb1, tid);
}

// ---------------------------------------------------------------------------
// Kernel 4: out[b][t] = mask * (sum over 22 wave-slots + c0)
// wave-slot bases: L:0(8), E:8(2), A:10(4), I:14(8)
// ---------------------------------------------------------------------------
__global__ void fuse_out(const float* __restrict__ sp, const float* __restrict__ v,
                         const float* __restrict__ masks, float* __restrict__ out) {
    int i = threadIdx.x + blockIdx.x * 256;
    int b = i >> 9, t = i & 511;
    int bg = b >> 4, bl = b & 15;
    float c0 = v[340];
    float s = 0.f;
#pragma unroll
    for (int sl = 0; sl < 22; sl++)
        s += sp[(size_t)((sl << 2) + bg) * 8192 + (t << 4) + bl];
    out[i] = masks[i] * (s + c0);
}

// ---------------------------------------------------------------------------
extern "C" void kernel_launch(void* const* d_in, const int* in_sizes, int n_in,
                              void* d_out, int out_size, void* d_ws, size_t ws_size,
                              hipStream_t stream) {
    const float* xL = (const float*)d_in[0];
    const int*   pL = (const int*)d_in[1];
    const float* WihL = (const float*)d_in[2];
    const float* WhhL = (const float*)d_in[3];
    const float* bihL = (const float*)d_in[4];
    const float* bhhL = (const float*)d_in[5];
    const float* xE = (const float*)d_in[6];
    const int*   pE = (const int*)d_in[7];
    const float* WihE = (const float*)d_in[8];
    const float* WhhE = (const float*)d_in[9];
    const float* bihE = (const float*)d_in[10];
    const float* bhhE = (const float*)d_in[11];
    const float* xA = (const float*)d_in[12];
    const int*   pA = (const int*)d_in[13];
    const float* WihA = (const float*)d_in[14];
    const float* WhhA = (const float*)d_in[15];
    const float* bihA = (const float*)d_in[16];
    const float* bhhA = (const float*)d_in[17];
    const float* xI = (const float*)d_in[18];
    const int*   pI = (const int*)d_in[19];
    const float* WihI = (const float*)d_in[20];
    const float* WhhI = (const float*)d_in[21];
    const float* bihI = (const float*)d_in[22];
    const float* bhhI = (const float*)d_in[23];
    const float* masks = (const float*)d_in[25];
    const float* fW1 = (const float*)d_in[26];
    const float* fb1 = (const float*)d_in[27];
    const float* fW2 = (const float*)d_in[28];
    const float* fb2 = (const float*)d_in[29];

    char* ws = (char*)d_ws;
    float* v     = (float*)ws;                           // 344 floats
    float* spart = (float*)(ws + (1 << 16));             // 88 * 8192 floats = 2.75 MB
    char* xgbase = ws + (1 << 16) + (3 << 20);
    fp16_t* xgL = (fp16_t*)xgbase;                            // 512*4*128*64 fp16 = 32 MB
    fp16_t* xgI = xgL + (size_t)512 * 4 * 128 * 64;           // 32 MB
    fp16_t* xgA = xgI + (size_t)512 * 4 * 128 * 64;           // 16 MB
    fp16_t* xgE = xgA + (size_t)512 * 4 * 64 * 64;            // 8 MB

    prep_fuse<<<dim3(1), dim3(512), 0, stream>>>(fW1, fb1, fW2, fb2, v);

    GemmArgs ga;
    ga.m[0] = {xL, WihL, bihL, bhhL, xgL, 300,  10, 512, 128, 7};
    ga.m[1] = {xE, WihE, bihE, bhhE, xgE, 30,   1,  80,  32,  0};
    ga.m[2] = {xA, WihA, bihA, bhhA, xgA, 88,   3,  256, 64,  6};
    ga.m[3] = {xI, WihI, bihI, bhhI, xgI, 1000, 32, 512, 128, 7};
    const int mi_tab[11] = {0, 0, 0, 0, 3, 3, 3, 3, 2, 2, 1};
    const int nb_tab[11] = {0, 1, 2, 3, 0, 1, 2, 3, 0, 1, 0};
    for (int i = 0; i < 11; i++) { ga.slot_mi[i] = mi_tab[i]; ga.slot_nb[i] = nb_tab[i]; }
    gemm_all<<<dim3(128, 11), dim3(512), 0, stream>>>(ga);

    RecArgs ra;
    ra.m[0] = {WhhL, pL, xgL, 0,   0};
    ra.m[1] = {WhhE, pE, xgE, 128, 8};
    ra.m[2] = {WhhA, pA, xgA, 148, 10};
    ra.m[3] = {WhhI, pI, xgI, 212, 14};
    ra.vvec = v;
    ra.spart = spart;
    rec_all<<<dim3(16), dim3(512), 0, stream>>>(ra);

    fuse_out<<<dim3(128), dim3(256), 0, stream>>>(spart, v, masks, (float*)d_out);
}